// Round 14
// baseline (214.906 us; speedup 1.0000x reference)
//
#include <hip/hip_runtime.h>
#include <hip/hip_bf16.h>
#include <stdint.h>

typedef unsigned short u16;
typedef unsigned int u32;
typedef __attribute__((ext_vector_type(8))) short bf16x8;
typedef __attribute__((ext_vector_type(4))) float f32x4;
typedef __attribute__((address_space(1))) unsigned int as1u;
typedef __attribute__((address_space(3))) unsigned int as3u;

#define DEV __device__ __forceinline__

DEV u16 f2bf(float f) {
  union { float f; unsigned u; } v; v.f = f;
  unsigned r = v.u + 0x7FFFu + ((v.u >> 16) & 1u);  // RNE
  return (u16)(r >> 16);
}

// hardware packed fp32->bf16 convert (no builtin on gfx950)
DEV u32 cvtpk(float lo, float hi) {
  u32 r;
  asm("v_cvt_pk_bf16_f32 %0, %1, %2" : "=v"(r) : "v"(lo), "v"(hi));
  return r;
}

// bare v_exp_f32 (2^x); args bounded above, underflow-to-0 desired.
DEV float fexp2(float x) {
  float r;
  asm("v_exp_f32 %0, %1" : "=v"(r) : "v"(x));
  return r;
}

DEV void gl_lds16(const void* g, void* l) {
  __builtin_amdgcn_global_load_lds(
      reinterpret_cast<as1u*>(reinterpret_cast<uintptr_t>(g)),
      reinterpret_cast<as3u*>(reinterpret_cast<uintptr_t>(l)), 16, 0, 0);
}

// XOR-swizzled index helpers. Tiles are [rows][64] elements.
DEV int swzh(int r, int c) { return r * 64 + (c ^ ((r & 7) << 3)); }

// XCD swizzle for 512-block GEMM grids.
DEV int xcdswz512(int bid) { return ((bid & 7) << 6) | (bid >> 3); }

// ---------------- weight transpose+convert (all 4 weights, z-indexed) ------
__global__ __launch_bounds__(256) void wtrans4_k(
    const float* __restrict__ W0, const float* __restrict__ W1,
    const float* __restrict__ W2, const float* __restrict__ W3,
    u16* __restrict__ T0, u16* __restrict__ T1, u16* __restrict__ T2,
    u16* __restrict__ T3) {
  const int z = blockIdx.z;
  const float* W = z == 0 ? W0 : z == 1 ? W1 : z == 2 ? W2 : W3;
  u16* Wt = z == 0 ? T0 : z == 1 ? T1 : z == 2 ? T2 : T3;
  __shared__ float t[64][65];
  const int tid = threadIdx.x;
  const int n0 = blockIdx.x * 64, k0 = blockIdx.y * 64;
  const int c = tid & 63, r4 = tid >> 6;
#pragma unroll
  for (int i = 0; i < 16; ++i) {
    int r = r4 * 16 + i;
    t[r][c] = W[(size_t)(k0 + r) * 1024 + n0 + c];
  }
  __syncthreads();
#pragma unroll
  for (int i = 0; i < 16; ++i) {
    int r = r4 * 16 + i;
    Wt[(size_t)(n0 + r) * 1024 + k0 + c] = f2bf(t[c][r]);
  }
}

// ---------------- fused QKV GEMM, fp32 A reg-staged (COALESCED this time) --
// A fp32 [8192][1024]; Bt bf16 [1024][1024]. z=0:K, 1:V(transposed out), 2:Q.
// Per K-step: {loadA(t+1)->regs (lane-coalesced), stageB(t+1)->LDS} at top;
// compute(t); writeA(t+1): cvtpk + swizzled ds_write_b64 (loads had the full
// MFMA block to land); one __syncthreads publishes A(ds)+B(gl_lds).
// R9's failure was loadA's arow=tid>>1 (each lane touching a different 4KB
// row -> 32 transactions/load). Now lanes 0-15 cover one 256B row: coalesced.
__global__ __launch_bounds__(256) void qkvgemm_k(
    const float* __restrict__ Akey, const float* __restrict__ Aval,
    const float* __restrict__ Aqry, const u16* __restrict__ BtK,
    const u16* __restrict__ BtV, const u16* __restrict__ BtQ,
    const float* __restrict__ bk, const float* __restrict__ bv,
    const float* __restrict__ bq, u16* __restrict__ Kup, u16* __restrict__ Vt,
    u16* __restrict__ Qup, float qscale) {
  constexpr int K = 1024;
  const int z = blockIdx.z;
  const float* Af = z == 0 ? Akey : z == 1 ? Aval : Aqry;
  const u16* Bt = z == 0 ? BtK : z == 1 ? BtV : BtQ;
  const float* bias = z == 0 ? bk : z == 1 ? bv : bq;
  u16* Cp = z == 0 ? Kup : z == 1 ? Vt : Qup;
  const float scale = z == 2 ? qscale : 1.0f;

  __shared__ alignas(16) char smem[65536];  // [buf][A bf16 16K | B 16K]

  const int tid = threadIdx.x;
  const int lane = tid & 63, wid = tid >> 6;
  const int swz = xcdswz512(blockIdx.x);
  const int brow = (swz >> 3) * 128;
  const int bcol = (swz & 7) * 128;
  const int wr = (wid >> 1) * 64, wc = (wid & 1) * 64;

  // A staging slice: i-th pass row = i*16 + (tid>>4), 4 fp32 at (tid&15)*4.
  const int arow = tid >> 4;          // 0..15
  const int acol = (tid & 15) * 4;    // fp32 elements

  f32x4 acc[4][4] = {};
  float4 fl[8];

  auto loadA = [&](int kt) {
#pragma unroll
    for (int i = 0; i < 8; ++i)
      fl[i] = *(const float4*)(Af + (size_t)(brow + i * 16 + arow) * K + kt +
                               acol);
  };
  auto writeA = [&](int buf) {
    char* dst = smem + buf * 32768;
#pragma unroll
    for (int i = 0; i < 8; ++i) {
      const int row = i * 16 + arow;
      uint2 v;
      v.x = cvtpk(fl[i].x, fl[i].y);
      v.y = cvtpk(fl[i].z, fl[i].w);
      *(uint2*)(dst + row * 128 + ((acol * 2) ^ ((row & 7) << 4))) = v;
    }
  };
  auto stageB = [&](int kt, int buf) {
#pragma unroll
    for (int i = 0; i < 4; ++i) {
      int row = i * 32 + (tid >> 3);
      const int sc = ((tid & 7) ^ (row & 7)) << 3;
      gl_lds16(Bt + (size_t)(bcol + row) * K + kt + sc,
               smem + buf * 32768 + 16384 + i * 4096 + wid * 1024);
    }
  };

  loadA(0);
  stageB(0, 0);
  writeA(0);  // waits its own loads (cold, once)
  __syncthreads();

  int cur = 0;
  for (int kt = 0; kt < K; kt += 64) {
    const bool next = (kt + 64 < K);
    if (next) {
      loadA(kt + 64);
      stageB(kt + 64, cur ^ 1);
    }
    const u16* Ash = (const u16*)(smem + cur * 32768);
    const u16* Bs = (const u16*)(smem + cur * 32768 + 16384);
#pragma unroll
    for (int kk = 0; kk < 2; ++kk) {
      const int kcol = kk * 32 + (lane >> 4) * 8;
      bf16x8 a[4], bfr[4];
#pragma unroll
      for (int m = 0; m < 4; ++m)
        a[m] = *(const bf16x8*)(Ash + swzh(wr + m * 16 + (lane & 15), kcol));
#pragma unroll
      for (int n = 0; n < 4; ++n)
        bfr[n] = *(const bf16x8*)(Bs + swzh(wc + n * 16 + (lane & 15), kcol));
#pragma unroll
      for (int m = 0; m < 4; ++m)
#pragma unroll
        for (int n = 0; n < 4; ++n)
          acc[m][n] = __builtin_amdgcn_mfma_f32_16x16x32_bf16(
              a[m], bfr[n], acc[m][n], 0, 0, 0);
    }
    if (next) writeA(cur ^ 1);  // loads landed during MFMA block
    __syncthreads();
    cur ^= 1;
  }

  const int g = lane >> 4;
  if (z == 1) {
    // V: LDS transpose -> coalesced stores along l
    u16* T = (u16*)smem;
#pragma unroll
    for (int m = 0; m < 4; ++m) {
      const int row0 = wr + m * 16 + g * 4;  // l_local
#pragma unroll
      for (int n = 0; n < 4; ++n) {
        const int col = wc + n * 16 + (lane & 15);  // dh_local
        const float bv2 = bias[bcol + col];
        uint2 p;
        p.x = cvtpk(acc[m][n][0] + bv2, acc[m][n][1] + bv2);
        p.y = cvtpk(acc[m][n][2] + bv2, acc[m][n][3] + bv2);
        *(uint2*)((char*)T + col * 256 + ((row0 * 2) ^ ((col & 7) << 4))) = p;
      }
    }
    __syncthreads();
    const int bI = brow >> 11, l0 = brow & 2047;
#pragma unroll
    for (int i = 0; i < 8; ++i) {
      const int rr = i * 16 + (tid >> 4);
      const int xb = (tid & 15) * 16;
      uint4 v = *(uint4*)((char*)T + rr * 256 + (xb ^ ((rr & 7) << 4)));
      const int colg = bcol + rr;
      const int hh = colg >> 6, dh = colg & 63;
      *(uint4*)(&Cp[((size_t)((bI << 4) + hh) * 64 + dh) * 2048 + l0 +
                    (xb >> 1)]) = v;
    }
  } else {
#pragma unroll
    for (int m = 0; m < 4; ++m) {
      const int row0 = brow + wr + m * 16 + (g << 2);
#pragma unroll
      for (int n = 0; n < 4; ++n) {
        const int col = bcol + wc + n * 16 + (lane & 15);
        const float bv2 = bias[col];
        const int h = col >> 6, dh = col & 63;
#pragma unroll
        for (int r = 0; r < 4; ++r) {
          const int row = row0 + r;
          const float val = (acc[m][n][r] + bv2) * scale;
          const int b = row >> 11, l = row & 2047;
          Cp[((size_t)((b << 4) + h) * 2048 + l) * 64 + dh] = f2bf(val);
        }
      }
    }
  }
}

// ---------------- output GEMM: counted-vmcnt dbuf (R12, measured-equal) ----
__global__ __launch_bounds__(256) void outgemm_k(const u16* __restrict__ Ah,
                                                 const u16* __restrict__ Bt,
                                                 const float* __restrict__ bias,
                                                 float* __restrict__ Cp) {
  constexpr int K = 1024;
  __shared__ alignas(16) char smem[65536];

  const int tid = threadIdx.x;
  const int lane = tid & 63, wid = tid >> 6;
  const int swz = xcdswz512(blockIdx.x);
  const int brow = (swz >> 3) * 128;
  const int bcol = (swz & 7) * 128;
  const int wr = (wid >> 1) * 64, wc = (wid & 1) * 64;

  f32x4 acc[4][4] = {};

  auto stage = [&](int kt, int buf) {
#pragma unroll
    for (int i = 0; i < 4; ++i) {
      int row = i * 32 + (tid >> 3);
      const int sc = ((tid & 7) ^ (row & 7)) << 3;
      gl_lds16(Ah + (size_t)(brow + row) * K + kt + sc,
               smem + buf * 32768 + i * 4096 + wid * 1024);
      gl_lds16(Bt + (size_t)(bcol + row) * K + kt + sc,
               smem + buf * 32768 + 16384 + i * 4096 + wid * 1024);
    }
  };

  stage(0, 0);
  stage(64, 1);

  int cur = 0;
  for (int kt = 0; kt < K; kt += 64) {
    if (kt == K - 64)
      asm volatile("s_waitcnt vmcnt(0)" ::: "memory");
    else
      asm volatile("s_waitcnt vmcnt(8)" ::: "memory");
    __builtin_amdgcn_s_barrier();

    const u16* Ash = (const u16*)(smem + cur * 32768);
    const u16* Bs = (const u16*)(smem + cur * 32768 + 16384);
#pragma unroll
    for (int kk = 0; kk < 2; ++kk) {
      const int kcol = kk * 32 + (lane >> 4) * 8;
      bf16x8 a[4], bfr[4];
#pragma unroll
      for (int m = 0; m < 4; ++m)
        a[m] = *(const bf16x8*)(Ash + swzh(wr + m * 16 + (lane & 15), kcol));
#pragma unroll
      for (int n = 0; n < 4; ++n)
        bfr[n] = *(const bf16x8*)(Bs + swzh(wc + n * 16 + (lane & 15), kcol));
#pragma unroll
      for (int m = 0; m < 4; ++m)
#pragma unroll
        for (int n = 0; n < 4; ++n)
          acc[m][n] = __builtin_amdgcn_mfma_f32_16x16x32_bf16(
              a[m], bfr[n], acc[m][n], 0, 0, 0);
    }
    asm volatile("s_waitcnt lgkmcnt(0)" ::: "memory");
    __builtin_amdgcn_s_barrier();
    if (kt + 128 < K) stage(kt + 128, cur);
    cur ^= 1;
  }

#pragma unroll
  for (int m = 0; m < 4; ++m) {
    const int row0 = brow + wr + m * 16 + ((lane >> 4) << 2);
#pragma unroll
    for (int n = 0; n < 4; ++n) {
      const int col = bcol + wc + n * 16 + (lane & 15);
      const float bv2 = bias[col];
#pragma unroll
      for (int r = 0; r < 4; ++r)
        Cp[(size_t)(row0 + r) * 1024 + col] = acc[m][n][r] + bv2;
    }
  }
}

// ---------------- flash attention: KVBLK=128, MFMA l-sum (unchanged) -------
__global__ __launch_bounds__(512, 4) void attn_k(const u16* __restrict__ Q,
                                                 const u16* __restrict__ K,
                                                 const u16* __restrict__ Vt,
                                                 u16* __restrict__ ctx,
                                                 float2* __restrict__ stats) {
  const int tid = threadIdx.x, lane = tid & 63, wid = tid >> 6;
  const int bh = blockIdx.x;
  const int qt = 15 - (int)blockIdx.y;  // heavy blocks first
  const int b = bh >> 4, h = bh & 15;
  const size_t base = (size_t)bh * 2048 * 64;

  __shared__ alignas(16) u16 Ks[2][8192], Vs[2][8192], Ps[8192];

  bf16x8 qf[2];
  {
    const u16* qp = Q + base +
                    (size_t)(qt * 128 + wid * 16 + (lane & 15)) * 64 +
                    ((lane >> 4) << 3);
    qf[0] = *(const bf16x8*)(qp);
    qf[1] = *(const bf16x8*)(qp + 32);
  }
  bf16x8 ones;
#pragma unroll
  for (int i = 0; i < 8; ++i) ones[i] = (short)0x3F80;  // bf16 1.0

  const int srowK = tid >> 3;
  const int scolK = ((tid & 7) ^ (srowK & 7)) << 3;
  const int srowV = tid >> 4;
  const int scolV = ((tid & 15) ^ (srowV & 7)) << 3;
  auto stage = [&](int kt, int buf) {
#pragma unroll
    for (int i = 0; i < 2; ++i)
      gl_lds16(K + base + (size_t)(kt * 128 + i * 64 + srowK) * 64 + scolK,
               (char*)Ks + buf * 16384 + i * 8192 + tid * 16);
#pragma unroll
    for (int i = 0; i < 2; ++i)
      gl_lds16(Vt + base + (size_t)(i * 32 + srowV) * 2048 + kt * 128 + scolV,
               (char*)Vs + buf * 16384 + i * 8192 + tid * 16);
  };

  f32x4 acc_o[4] = {}, acc_l = {};
  float m_run = -1e30f;
  const int q = qt * 128 + wid * 16 + (lane & 15);
  const int g = lane >> 4;
  const int l7 = lane & 7;

  stage(0, 0);
  __syncthreads();

  int cur = 0;
  for (int kt = 0; kt <= qt; ++kt) {
    if (kt < qt) stage(kt + 1, cur ^ 1);

    f32x4 s[8] = {};
#pragma unroll
    for (int kk = 0; kk < 2; ++kk) {
      const int kcb = kk * 64 + g * 16;
#pragma unroll
      for (int n2 = 0; n2 < 8; ++n2) {
        const int row = n2 * 16 + (lane & 15);
        bf16x8 kf = *(const bf16x8*)((char*)Ks + cur * 16384 + row * 128 +
                                     (kcb ^ ((row & 7) << 4)));
        s[n2] = __builtin_amdgcn_mfma_f32_16x16x32_bf16(kf, qf[kk], s[n2],
                                                        0, 0, 0);
      }
    }

    if (kt == qt) {  // diagonal tile: mask kv > q
      const int kb = kt * 128 + g * 4;
#pragma unroll
      for (int n2 = 0; n2 < 8; ++n2)
#pragma unroll
        for (int r = 0; r < 4; ++r)
          if (kb + n2 * 16 + r > q) s[n2][r] = -1e30f;
    }

    float mn0 = fmaxf(fmaxf(fmaxf(s[0][0], s[0][1]), fmaxf(s[0][2], s[0][3])),
                      fmaxf(fmaxf(s[1][0], s[1][1]), fmaxf(s[1][2], s[1][3])));
    float mn1 = fmaxf(fmaxf(fmaxf(s[2][0], s[2][1]), fmaxf(s[2][2], s[2][3])),
                      fmaxf(fmaxf(s[3][0], s[3][1]), fmaxf(s[3][2], s[3][3])));
    float mn2 = fmaxf(fmaxf(fmaxf(s[4][0], s[4][1]), fmaxf(s[4][2], s[4][3])),
                      fmaxf(fmaxf(s[5][0], s[5][1]), fmaxf(s[5][2], s[5][3])));
    float mn3 = fmaxf(fmaxf(fmaxf(s[6][0], s[6][1]), fmaxf(s[6][2], s[6][3])),
                      fmaxf(fmaxf(s[7][0], s[7][1]), fmaxf(s[7][2], s[7][3])));
    float mx = fmaxf(fmaxf(mn0, mn1), fmaxf(mn2, mn3));
    mx = fmaxf(mx, __shfl_xor(mx, 16, 64));
    mx = fmaxf(mx, __shfl_xor(mx, 32, 64));

    if (__any(mx - m_run > 8.0f)) {  // defer-max (log2 units)
      const float mn = fmaxf(m_run, mx);
      const float alpha = fexp2(m_run - mn);
      m_run = mn;
#pragma unroll
      for (int r = 0; r < 4; ++r) {
        const float ar = __shfl(alpha, (g << 2) + r, 64);
        acc_l[r] *= ar;
#pragma unroll
        for (int n = 0; n < 4; ++n) acc_o[n][r] *= ar;
      }
    }

#pragma unroll
    for (int n2 = 0; n2 < 8; ++n2)
#pragma unroll
      for (int r = 0; r < 4; ++r) s[n2][r] = fexp2(s[n2][r] - m_run);

#pragma unroll
    for (int hf = 0; hf < 2; ++hf) {
#pragma unroll
      for (int n3 = 0; n3 < 4; ++n3) {
        const int n2 = hf * 4 + n3;
        union { u32 w[2]; uint2 u; } pk;
        pk.w[0] = cvtpk(s[n2][0], s[n2][1]);
        pk.w[1] = cvtpk(s[n2][2], s[n2][3]);
        *(uint2*)((char*)Ps + wid * 2048 + (lane & 15) * 128 +
                  ((n3 * 32 + g * 8) ^ (l7 << 4))) = pk.u;
      }
#pragma unroll
      for (int kk2 = 0; kk2 < 2; ++kk2) {
        bf16x8 pf = *(const bf16x8*)((char*)Ps + wid * 2048 +
                                     (lane & 15) * 128 +
                                     ((kk2 * 64 + g * 16) ^ (l7 << 4)));
        const int kvb = hf * 128 + kk2 * 64 + g * 16;
#pragma unroll
        for (int n = 0; n < 4; ++n) {
          const int dh = n * 16 + (lane & 15);
          bf16x8 vf = *(const bf16x8*)((char*)Vs + cur * 16384 + dh * 256 +
                                       (kvb ^ ((dh & 7) << 4)));
          acc_o[n] = __builtin_amdgcn_mfma_f32_16x16x32_bf16(pf, vf, acc_o[n],
                                                             0, 0, 0);
        }
        acc_l = __builtin_amdgcn_mfma_f32_16x16x32_bf16(pf, ones, acc_l,
                                                        0, 0, 0);
      }
    }
    __syncthreads();
    cur ^= 1;
  }

#pragma unroll
  for (int r = 0; r < 4; ++r) {
    const float linv = __builtin_amdgcn_rcpf(acc_l[r]);
    const int qo = qt * 128 + wid * 16 + (g << 2) + r;
#pragma unroll
    for (int n = 0; n < 4; ++n) {
      const int dh = n * 16 + (lane & 15);
      ctx[((size_t)(b * 2048 + qo)) * 1024 + h * 64 + dh] =
          f2bf(acc_o[n][r] * linv);
    }
  }
  if (h == 0) {
    float mr[4];
#pragma unroll
    for (int r = 0; r < 4; ++r) mr[r] = __shfl(m_run, (g << 2) + r, 64);
    if ((lane & 15) == 0) {
#pragma unroll
      for (int r = 0; r < 4; ++r) {
        const int qo = qt * 128 + wid * 16 + (g << 2) + r;
        stats[b * 2048 + qo] = make_float2(mr[r], acc_l[r]);
      }
    }
  }
}

// ---------------- top_attn (head 0): LDS transpose -> float4 stores --------
__global__ __launch_bounds__(256) void probs_k(const u16* __restrict__ Q,
                                               const u16* __restrict__ K,
                                               const float2* __restrict__ stats,
                                               float* __restrict__ out) {
  const int tid = threadIdx.x, lane = tid & 63, wid = tid >> 6;
  const int kt2 = blockIdx.x, qt = blockIdx.y, b = blockIdx.z;
  const int q0 = qt * 64, c0 = kt2 * 128;
  float* ot = out + ((size_t)b * 2048 + q0) * 2048 + c0;

  if (c0 > q0 + 63) {  // whole tile masked -> zero-fill
    const float4 z = make_float4(0.f, 0.f, 0.f, 0.f);
#pragma unroll
    for (int i = 0; i < 8; ++i) {
      const int idx = i * 256 + tid;
      *(float4*)(ot + (size_t)(idx >> 5) * 2048 + ((idx & 31) << 2)) = z;
    }
    return;
  }

  __shared__ alignas(16) char sm[32768];
  u16* Qs = (u16*)sm;            // 8KB
  u16* Ks2 = (u16*)(sm + 8192);  // 16KB
  float* Pt = (float*)sm;        // 32KB reuse after compute

  const size_t base = (size_t)(b * 16) * 2048 * 64;  // h = 0
#pragma unroll
  for (int i = 0; i < 2; ++i) {
    int row = i * 32 + (tid >> 3);
    gl_lds16(Q + base + (size_t)(q0 + row) * 64 + (((tid & 7) ^ (row & 7)) << 3),
             (char*)Qs + i * 4096 + wid * 1024);
  }
#pragma unroll
  for (int i = 0; i < 4; ++i) {
    int row = i * 32 + (tid >> 3);
    gl_lds16(K + base + (size_t)(c0 + row) * 64 + (((tid & 7) ^ (row & 7)) << 3),
             (char*)Ks2 + i * 4096 + wid * 1024);
  }
  __syncthreads();

  f32x4 s[8] = {};
#pragma unroll
  for (int kk = 0; kk < 2; ++kk) {
    const int kc = kk * 32 + (lane >> 4) * 8;
    bf16x8 aq = *(const bf16x8*)(Qs + swzh(wid * 16 + (lane & 15), kc));
#pragma unroll
    for (int n = 0; n < 8; ++n) {
      bf16x8 bk = *(const bf16x8*)(Ks2 + swzh(n * 16 + (lane & 15), kc));
      s[n] = __builtin_amdgcn_mfma_f32_16x16x32_bf16(aq, bk, s[n], 0, 0, 0);
    }
  }
  __syncthreads();  // staging LDS dead; reuse as Pt

  // write P into LDS [64 q][128 kp] fp32, dword-XOR swizzled per 16B group
#pragma unroll
  for (int r = 0; r < 4; ++r) {
    const int ql = wid * 16 + ((lane >> 4) << 2) + r;
    const int qg = q0 + ql;
    const float2 st = stats[b * 2048 + qg];
    const float rl = __builtin_amdgcn_rcpf(st.y);
#pragma unroll
    for (int n = 0; n < 8; ++n) {
      const int kp = n * 16 + (lane & 15);
      const float v = (c0 + kp <= qg) ? fexp2(s[n][r] - st.x) * rl : 0.f;
      Pt[ql * 128 + (kp ^ ((ql & 7) << 2))] = v;
    }
  }
  __syncthreads();

  // coalesced stores: thread -> row tid>>2, 32-col slab (tid&3)*32
  const int rr = tid >> 2;
  const int c00 = (tid & 3) * 32;
  float* orow = out + ((size_t)b * 2048 + q0 + rr) * 2048 + c0 + c00;
#pragma unroll
  for (int j = 0; j < 8; ++j) {
    const int c = c00 + j * 4;
    float4 v = *(float4*)&Pt[rr * 128 + (c ^ ((rr & 7) << 2))];
    *(float4*)(orow + j * 4) = v;
  }
}

extern "C" void kernel_launch(void* const* d_in, const int* in_sizes, int n_in,
                              void* d_out, int out_size, void* d_ws,
                              size_t ws_size, hipStream_t stream) {
  (void)in_sizes; (void)n_in; (void)out_size; (void)ws_size;
  const float* key = (const float*)d_in[0];
  const float* value = (const float*)d_in[1];
  const float* query = (const float*)d_in[2];
  const float* Wk = (const float*)d_in[4];
  const float* bk = (const float*)d_in[5];
  const float* Wv = (const float*)d_in[6];
  const float* bv = (const float*)d_in[7];
  const float* Wq = (const float*)d_in[8];
  const float* bq = (const float*)d_in[9];
  const float* Wo = (const float*)d_in[10];
  const float* bo = (const float*)d_in[11];

  char* ws = (char*)d_ws;  // needs ~76 MB
  u16* WtK = (u16*)(ws);
  u16* WtV = (u16*)(ws + (2u << 20));
  u16* WtQ = (u16*)(ws + (4u << 20));
  u16* WtO = (u16*)(ws + (6u << 20));
  u16* Kup = (u16*)(ws + (8u << 20));   // [b][h][l][dh] bf16
  u16* Qup = (u16*)(ws + (24u << 20));  // [b][h][l][dh] bf16
  u16* Vt  = (u16*)(ws + (40u << 20));  // [b][h][dh][l] bf16
  u16* ctx = (u16*)(ws + (56u << 20));  // [b][l][1024] bf16
  float2* stats = (float2*)(ws + (72u << 20));  // [b*2048] (m_log2, lsum)

  wtrans4_k<<<dim3(16, 16, 4), 256, 0, stream>>>(Wk, Wv, Wq, Wo, WtK, WtV,
                                                 WtQ, WtO);

  // Q scale folds 1/sqrt(DH) and log2(e) so softmax runs on exp2 directly.
  const float qscale = 0.125f * 1.44269504088896340736f;
  qkvgemm_k<<<dim3(512, 1, 3), 256, 0, stream>>>(
      key, value, query, WtK, WtV, WtQ, bk, bv, bq, Kup, Vt, Qup, qscale);

  attn_k<<<dim3(64, 16), 512, 0, stream>>>(Qup, Kup, Vt, ctx, stats);

  float* out = (float*)d_out;
  probs_k<<<dim3(16, 32, 4), 256, 0, stream>>>(Qup, Kup, stats,
                                               out + (size_t)8388608);

  outgemm_k<<<512, 256, 0, stream>>>(ctx, WtO, bo, out);
}

// Round 15
// 190.046 us; speedup vs baseline: 1.1308x; 1.1308x over previous
//
#include <hip/hip_runtime.h>
#include <hip/hip_bf16.h>
#include <stdint.h>

typedef unsigned short u16;
typedef unsigned int u32;
typedef __attribute__((ext_vector_type(8))) short bf16x8;
typedef __attribute__((ext_vector_type(4))) float f32x4;
typedef __attribute__((address_space(1))) unsigned int as1u;
typedef __attribute__((address_space(3))) unsigned int as3u;

#define DEV __device__ __forceinline__

DEV u16 f2bf(float f) {
  union { float f; unsigned u; } v; v.f = f;
  unsigned r = v.u + 0x7FFFu + ((v.u >> 16) & 1u);  // RNE
  return (u16)(r >> 16);
}

// hardware packed fp32->bf16 convert (no builtin on gfx950)
DEV u32 cvtpk(float lo, float hi) {
  u32 r;
  asm("v_cvt_pk_bf16_f32 %0, %1, %2" : "=v"(r) : "v"(lo), "v"(hi));
  return r;
}

// bare v_exp_f32 (2^x); args bounded above, underflow-to-0 desired.
DEV float fexp2(float x) {
  float r;
  asm("v_exp_f32 %0, %1" : "=v"(r) : "v"(x));
  return r;
}

DEV void gl_lds16(const void* g, void* l) {
  __builtin_amdgcn_global_load_lds(
      reinterpret_cast<as1u*>(reinterpret_cast<uintptr_t>(g)),
      reinterpret_cast<as3u*>(reinterpret_cast<uintptr_t>(l)), 16, 0, 0);
}

// XOR-swizzled index helpers. Tiles are [rows][64] elements.
DEV int swzh(int r, int c) { return r * 64 + (c ^ ((r & 7) << 3)); }

// XCD swizzle for 512-block GEMM grids.
DEV int xcdswz512(int bid) { return ((bid & 7) << 6) | (bid >> 3); }

// ---------------- prep: weight transpose (z 0-3) + A fp32->bf16 (z 4-6) ----
// Merged so the small BW-bound prep kernels co-schedule in one launch.
__global__ __launch_bounds__(256) void prep_k(
    const float* __restrict__ W0, const float* __restrict__ W1,
    const float* __restrict__ W2, const float* __restrict__ W3,
    u16* __restrict__ T0, u16* __restrict__ T1, u16* __restrict__ T2,
    u16* __restrict__ T3, const float* __restrict__ I0,
    const float* __restrict__ I1, const float* __restrict__ I2,
    u16* __restrict__ O0, u16* __restrict__ O1, u16* __restrict__ O2) {
  const int z = blockIdx.z;
  const int tid = threadIdx.x;
  if (z < 4) {
    if (blockIdx.x >= 256) return;
    const float* W = z == 0 ? W0 : z == 1 ? W1 : z == 2 ? W2 : W3;
    u16* Wt = z == 0 ? T0 : z == 1 ? T1 : z == 2 ? T2 : T3;
    __shared__ float t[64][65];
    const int n0 = (blockIdx.x & 15) * 64, k0 = (blockIdx.x >> 4) * 64;
    const int c = tid & 63, r4 = tid >> 6;
#pragma unroll
    for (int i = 0; i < 16; ++i) {
      int r = r4 * 16 + i;
      t[r][c] = W[(size_t)(k0 + r) * 1024 + n0 + c];
    }
    __syncthreads();
#pragma unroll
    for (int i = 0; i < 16; ++i) {
      int r = r4 * 16 + i;
      Wt[(size_t)(n0 + r) * 1024 + k0 + c] = f2bf(t[c][r]);
    }
  } else {
    const float* in = z == 4 ? I0 : z == 5 ? I1 : I2;
    u16* out = z == 4 ? O0 : z == 5 ? O1 : O2;
    const int idx = blockIdx.x * 256 + tid;  // 1024 blocks
#pragma unroll
    for (int j = 0; j < 8; ++j) {
      const int i = j * 262144 + idx;
      float4 x = ((const float4*)in)[i];
      uint2 p;
      p.x = cvtpk(x.x, x.y);
      p.y = cvtpk(x.z, x.w);
      ((uint2*)out)[i] = p;
    }
  }
}

// ---------------- fused QKV projection GEMM, bf16 A, counted-vmcnt dbuf ----
__global__ __launch_bounds__(256) void qkvgemm_k(
    const u16* __restrict__ Akey, const u16* __restrict__ Aval,
    const u16* __restrict__ Aqry, const u16* __restrict__ BtK,
    const u16* __restrict__ BtV, const u16* __restrict__ BtQ,
    const float* __restrict__ bk, const float* __restrict__ bv,
    const float* __restrict__ bq, u16* __restrict__ Kup, u16* __restrict__ Vt,
    u16* __restrict__ Qup, float qscale) {
  constexpr int K = 1024;
  const int z = blockIdx.z;
  const u16* Ah = z == 0 ? Akey : z == 1 ? Aval : Aqry;
  const u16* Bt = z == 0 ? BtK : z == 1 ? BtV : BtQ;
  const float* bias = z == 0 ? bk : z == 1 ? bv : bq;
  u16* Cp = z == 0 ? Kup : z == 1 ? Vt : Qup;
  const float scale = z == 2 ? qscale : 1.0f;

  __shared__ alignas(16) char smem[65536];  // [buf][A 16K | B 16K]

  const int tid = threadIdx.x;
  const int lane = tid & 63, wid = tid >> 6;
  const int swz = xcdswz512(blockIdx.x);
  const int brow = (swz >> 3) * 128;
  const int bcol = (swz & 7) * 128;
  const int wr = (wid >> 1) * 64, wc = (wid & 1) * 64;

  f32x4 acc[4][4] = {};

  auto stage = [&](int kt, int buf) {
#pragma unroll
    for (int i = 0; i < 4; ++i) {
      int row = i * 32 + (tid >> 3);
      const int sc = ((tid & 7) ^ (row & 7)) << 3;
      gl_lds16(Ah + (size_t)(brow + row) * K + kt + sc,
               smem + buf * 32768 + i * 4096 + wid * 1024);
      gl_lds16(Bt + (size_t)(bcol + row) * K + kt + sc,
               smem + buf * 32768 + 16384 + i * 4096 + wid * 1024);
    }
  };

  stage(0, 0);   // 8 loads/wave
  stage(64, 1);  // 8 more in flight

  int cur = 0;
  for (int kt = 0; kt < K; kt += 64) {
    if (kt == K - 64)
      asm volatile("s_waitcnt vmcnt(0)" ::: "memory");
    else
      asm volatile("s_waitcnt vmcnt(8)" ::: "memory");
    __builtin_amdgcn_s_barrier();  // tile kt visible to all waves

    const u16* Ash = (const u16*)(smem + cur * 32768);
    const u16* Bs = (const u16*)(smem + cur * 32768 + 16384);
#pragma unroll
    for (int kk = 0; kk < 2; ++kk) {
      const int kcol = kk * 32 + (lane >> 4) * 8;
      bf16x8 a[4], bfr[4];
#pragma unroll
      for (int m = 0; m < 4; ++m)
        a[m] = *(const bf16x8*)(Ash + swzh(wr + m * 16 + (lane & 15), kcol));
#pragma unroll
      for (int n = 0; n < 4; ++n)
        bfr[n] = *(const bf16x8*)(Bs + swzh(wc + n * 16 + (lane & 15), kcol));
#pragma unroll
      for (int m = 0; m < 4; ++m)
#pragma unroll
        for (int n = 0; n < 4; ++n)
          acc[m][n] = __builtin_amdgcn_mfma_f32_16x16x32_bf16(
              a[m], bfr[n], acc[m][n], 0, 0, 0);
    }
    asm volatile("s_waitcnt lgkmcnt(0)" ::: "memory");
    __builtin_amdgcn_s_barrier();  // all waves done reading buf cur
    if (kt + 128 < K) stage(kt + 128, cur);  // overwrite consumed buffer
    cur ^= 1;
  }

  const int g = lane >> 4;
  if (z == 1) {
    // V: LDS transpose -> coalesced stores along l
    u16* T = (u16*)smem;
#pragma unroll
    for (int m = 0; m < 4; ++m) {
      const int row0 = wr + m * 16 + g * 4;  // l_local
#pragma unroll
      for (int n = 0; n < 4; ++n) {
        const int col = wc + n * 16 + (lane & 15);  // dh_local
        const float bv2 = bias[bcol + col];
        uint2 p;
        p.x = cvtpk(acc[m][n][0] + bv2, acc[m][n][1] + bv2);
        p.y = cvtpk(acc[m][n][2] + bv2, acc[m][n][3] + bv2);
        *(uint2*)((char*)T + col * 256 + ((row0 * 2) ^ ((col & 7) << 4))) = p;
      }
    }
    __syncthreads();
    const int bI = brow >> 11, l0 = brow & 2047;
#pragma unroll
    for (int i = 0; i < 8; ++i) {
      const int rr = i * 16 + (tid >> 4);
      const int xb = (tid & 15) * 16;
      uint4 v = *(uint4*)((char*)T + rr * 256 + (xb ^ ((rr & 7) << 4)));
      const int colg = bcol + rr;
      const int hh = colg >> 6, dh = colg & 63;
      *(uint4*)(&Cp[((size_t)((bI << 4) + hh) * 64 + dh) * 2048 + l0 +
                    (xb >> 1)]) = v;
    }
  } else {
#pragma unroll
    for (int m = 0; m < 4; ++m) {
      const int row0 = brow + wr + m * 16 + (g << 2);
#pragma unroll
      for (int n = 0; n < 4; ++n) {
        const int col = bcol + wc + n * 16 + (lane & 15);
        const float bv2 = bias[col];
        const int h = col >> 6, dh = col & 63;
#pragma unroll
        for (int r = 0; r < 4; ++r) {
          const int row = row0 + r;
          const float val = (acc[m][n][r] + bv2) * scale;
          const int b = row >> 11, l = row & 2047;
          Cp[((size_t)((b << 4) + h) * 2048 + l) * 64 + dh] = f2bf(val);
        }
      }
    }
  }
}

// ---------------- output GEMM: counted-vmcnt dbuf --------------------------
__global__ __launch_bounds__(256) void outgemm_k(const u16* __restrict__ Ah,
                                                 const u16* __restrict__ Bt,
                                                 const float* __restrict__ bias,
                                                 float* __restrict__ Cp) {
  constexpr int K = 1024;
  __shared__ alignas(16) char smem[65536];

  const int tid = threadIdx.x;
  const int lane = tid & 63, wid = tid >> 6;
  const int swz = xcdswz512(blockIdx.x);
  const int brow = (swz >> 3) * 128;
  const int bcol = (swz & 7) * 128;
  const int wr = (wid >> 1) * 64, wc = (wid & 1) * 64;

  f32x4 acc[4][4] = {};

  auto stage = [&](int kt, int buf) {
#pragma unroll
    for (int i = 0; i < 4; ++i) {
      int row = i * 32 + (tid >> 3);
      const int sc = ((tid & 7) ^ (row & 7)) << 3;
      gl_lds16(Ah + (size_t)(brow + row) * K + kt + sc,
               smem + buf * 32768 + i * 4096 + wid * 1024);
      gl_lds16(Bt + (size_t)(bcol + row) * K + kt + sc,
               smem + buf * 32768 + 16384 + i * 4096 + wid * 1024);
    }
  };

  stage(0, 0);
  stage(64, 1);

  int cur = 0;
  for (int kt = 0; kt < K; kt += 64) {
    if (kt == K - 64)
      asm volatile("s_waitcnt vmcnt(0)" ::: "memory");
    else
      asm volatile("s_waitcnt vmcnt(8)" ::: "memory");
    __builtin_amdgcn_s_barrier();

    const u16* Ash = (const u16*)(smem + cur * 32768);
    const u16* Bs = (const u16*)(smem + cur * 32768 + 16384);
#pragma unroll
    for (int kk = 0; kk < 2; ++kk) {
      const int kcol = kk * 32 + (lane >> 4) * 8;
      bf16x8 a[4], bfr[4];
#pragma unroll
      for (int m = 0; m < 4; ++m)
        a[m] = *(const bf16x8*)(Ash + swzh(wr + m * 16 + (lane & 15), kcol));
#pragma unroll
      for (int n = 0; n < 4; ++n)
        bfr[n] = *(const bf16x8*)(Bs + swzh(wc + n * 16 + (lane & 15), kcol));
#pragma unroll
      for (int m = 0; m < 4; ++m)
#pragma unroll
        for (int n = 0; n < 4; ++n)
          acc[m][n] = __builtin_amdgcn_mfma_f32_16x16x32_bf16(
              a[m], bfr[n], acc[m][n], 0, 0, 0);
    }
    asm volatile("s_waitcnt lgkmcnt(0)" ::: "memory");
    __builtin_amdgcn_s_barrier();
    if (kt + 128 < K) stage(kt + 128, cur);
    cur ^= 1;
  }

#pragma unroll
  for (int m = 0; m < 4; ++m) {
    const int row0 = brow + wr + m * 16 + ((lane >> 4) << 2);
#pragma unroll
    for (int n = 0; n < 4; ++n) {
      const int col = bcol + wc + n * 16 + (lane & 15);
      const float bv2 = bias[col];
#pragma unroll
      for (int r = 0; r < 4; ++r)
        Cp[(size_t)(row0 + r) * 1024 + col] = acc[m][n][r] + bv2;
    }
  }
}

// ---------------- flash attention: KVBLK=128, MFMA l-sum -------------------
__global__ __launch_bounds__(512, 4) void attn_k(const u16* __restrict__ Q,
                                                 const u16* __restrict__ K,
                                                 const u16* __restrict__ Vt,
                                                 u16* __restrict__ ctx,
                                                 float2* __restrict__ stats) {
  const int tid = threadIdx.x, lane = tid & 63, wid = tid >> 6;
  const int bh = blockIdx.x;
  const int qt = 15 - (int)blockIdx.y;  // heavy blocks first
  const int b = bh >> 4, h = bh & 15;
  const size_t base = (size_t)bh * 2048 * 64;

  __shared__ alignas(16) u16 Ks[2][8192], Vs[2][8192], Ps[8192];

  bf16x8 qf[2];
  {
    const u16* qp = Q + base +
                    (size_t)(qt * 128 + wid * 16 + (lane & 15)) * 64 +
                    ((lane >> 4) << 3);
    qf[0] = *(const bf16x8*)(qp);
    qf[1] = *(const bf16x8*)(qp + 32);
  }
  bf16x8 ones;
#pragma unroll
  for (int i = 0; i < 8; ++i) ones[i] = (short)0x3F80;  // bf16 1.0

  const int srowK = tid >> 3;
  const int scolK = ((tid & 7) ^ (srowK & 7)) << 3;
  const int srowV = tid >> 4;
  const int scolV = ((tid & 15) ^ (srowV & 7)) << 3;
  auto stage = [&](int kt, int buf) {
#pragma unroll
    for (int i = 0; i < 2; ++i)
      gl_lds16(K + base + (size_t)(kt * 128 + i * 64 + srowK) * 64 + scolK,
               (char*)Ks + buf * 16384 + i * 8192 + tid * 16);
#pragma unroll
    for (int i = 0; i < 2; ++i)
      gl_lds16(Vt + base + (size_t)(i * 32 + srowV) * 2048 + kt * 128 + scolV,
               (char*)Vs + buf * 16384 + i * 8192 + tid * 16);
  };

  f32x4 acc_o[4] = {}, acc_l = {};
  float m_run = -1e30f;
  const int q = qt * 128 + wid * 16 + (lane & 15);
  const int g = lane >> 4;
  const int l7 = lane & 7;

  stage(0, 0);
  __syncthreads();

  int cur = 0;
  for (int kt = 0; kt <= qt; ++kt) {
    if (kt < qt) stage(kt + 1, cur ^ 1);

    f32x4 s[8] = {};
#pragma unroll
    for (int kk = 0; kk < 2; ++kk) {
      const int kcb = kk * 64 + g * 16;
#pragma unroll
      for (int n2 = 0; n2 < 8; ++n2) {
        const int row = n2 * 16 + (lane & 15);
        bf16x8 kf = *(const bf16x8*)((char*)Ks + cur * 16384 + row * 128 +
                                     (kcb ^ ((row & 7) << 4)));
        s[n2] = __builtin_amdgcn_mfma_f32_16x16x32_bf16(kf, qf[kk], s[n2],
                                                        0, 0, 0);
      }
    }

    if (kt == qt) {  // diagonal tile: mask kv > q
      const int kb = kt * 128 + g * 4;
#pragma unroll
      for (int n2 = 0; n2 < 8; ++n2)
#pragma unroll
        for (int r = 0; r < 4; ++r)
          if (kb + n2 * 16 + r > q) s[n2][r] = -1e30f;
    }

    float mn0 = fmaxf(fmaxf(fmaxf(s[0][0], s[0][1]), fmaxf(s[0][2], s[0][3])),
                      fmaxf(fmaxf(s[1][0], s[1][1]), fmaxf(s[1][2], s[1][3])));
    float mn1 = fmaxf(fmaxf(fmaxf(s[2][0], s[2][1]), fmaxf(s[2][2], s[2][3])),
                      fmaxf(fmaxf(s[3][0], s[3][1]), fmaxf(s[3][2], s[3][3])));
    float mn2 = fmaxf(fmaxf(fmaxf(s[4][0], s[4][1]), fmaxf(s[4][2], s[4][3])),
                      fmaxf(fmaxf(s[5][0], s[5][1]), fmaxf(s[5][2], s[5][3])));
    float mn3 = fmaxf(fmaxf(fmaxf(s[6][0], s[6][1]), fmaxf(s[6][2], s[6][3])),
                      fmaxf(fmaxf(s[7][0], s[7][1]), fmaxf(s[7][2], s[7][3])));
    float mx = fmaxf(fmaxf(mn0, mn1), fmaxf(mn2, mn3));
    mx = fmaxf(mx, __shfl_xor(mx, 16, 64));
    mx = fmaxf(mx, __shfl_xor(mx, 32, 64));

    if (__any(mx - m_run > 8.0f)) {  // defer-max (log2 units)
      const float mn = fmaxf(m_run, mx);
      const float alpha = fexp2(m_run - mn);
      m_run = mn;
#pragma unroll
      for (int r = 0; r < 4; ++r) {
        const float ar = __shfl(alpha, (g << 2) + r, 64);
        acc_l[r] *= ar;
#pragma unroll
        for (int n = 0; n < 4; ++n) acc_o[n][r] *= ar;
      }
    }

#pragma unroll
    for (int n2 = 0; n2 < 8; ++n2)
#pragma unroll
      for (int r = 0; r < 4; ++r) s[n2][r] = fexp2(s[n2][r] - m_run);

#pragma unroll
    for (int hf = 0; hf < 2; ++hf) {
#pragma unroll
      for (int n3 = 0; n3 < 4; ++n3) {
        const int n2 = hf * 4 + n3;
        union { u32 w[2]; uint2 u; } pk;
        pk.w[0] = cvtpk(s[n2][0], s[n2][1]);
        pk.w[1] = cvtpk(s[n2][2], s[n2][3]);
        *(uint2*)((char*)Ps + wid * 2048 + (lane & 15) * 128 +
                  ((n3 * 32 + g * 8) ^ (l7 << 4))) = pk.u;
      }
#pragma unroll
      for (int kk2 = 0; kk2 < 2; ++kk2) {
        bf16x8 pf = *(const bf16x8*)((char*)Ps + wid * 2048 +
                                     (lane & 15) * 128 +
                                     ((kk2 * 64 + g * 16) ^ (l7 << 4)));
        const int kvb = hf * 128 + kk2 * 64 + g * 16;
#pragma unroll
        for (int n = 0; n < 4; ++n) {
          const int dh = n * 16 + (lane & 15);
          bf16x8 vf = *(const bf16x8*)((char*)Vs + cur * 16384 + dh * 256 +
                                       (kvb ^ ((dh & 7) << 4)));
          acc_o[n] = __builtin_amdgcn_mfma_f32_16x16x32_bf16(pf, vf, acc_o[n],
                                                             0, 0, 0);
        }
        acc_l = __builtin_amdgcn_mfma_f32_16x16x32_bf16(pf, ones, acc_l,
                                                        0, 0, 0);
      }
    }
    __syncthreads();
    cur ^= 1;
  }

#pragma unroll
  for (int r = 0; r < 4; ++r) {
    const float linv = __builtin_amdgcn_rcpf(acc_l[r]);
    const int qo = qt * 128 + wid * 16 + (g << 2) + r;
#pragma unroll
    for (int n = 0; n < 4; ++n) {
      const int dh = n * 16 + (lane & 15);
      ctx[((size_t)(b * 2048 + qo)) * 1024 + h * 64 + dh] =
          f2bf(acc_o[n][r] * linv);
    }
  }
  if (h == 0) {
    float mr[4];
#pragma unroll
    for (int r = 0; r < 4; ++r) mr[r] = __shfl(m_run, (g << 2) + r, 64);
    if ((lane & 15) == 0) {
#pragma unroll
      for (int r = 0; r < 4; ++r) {
        const int qo = qt * 128 + wid * 16 + (g << 2) + r;
        stats[b * 2048 + qo] = make_float2(mr[r], acc_l[r]);
      }
    }
  }
}

// ---------------- top_attn (head 0) probabilities --------------------------
__global__ __launch_bounds__(256) void probs_k(const u16* __restrict__ Q,
                                               const u16* __restrict__ K,
                                               const float2* __restrict__ stats,
                                               float* __restrict__ out) {
  const int tid = threadIdx.x, lane = tid & 63, wid = tid >> 6;
  const int kt2 = blockIdx.x, qt = blockIdx.y, b = blockIdx.z;
  const int q0 = qt * 64, c0 = kt2 * 128;
  float* ot = out + ((size_t)b * 2048 + q0) * 2048 + c0;

  if (c0 > q0 + 63) {  // whole tile masked -> zero-fill
    const float4 z = make_float4(0.f, 0.f, 0.f, 0.f);
#pragma unroll
    for (int i = 0; i < 8; ++i) {
      const int idx = i * 256 + tid;
      *(float4*)(ot + (size_t)(idx >> 5) * 2048 + ((idx & 31) << 2)) = z;
    }
    return;
  }

  __shared__ alignas(16) u16 Qs[4096], Ks2[8192];
  const size_t base = (size_t)(b * 16) * 2048 * 64;  // h = 0
#pragma unroll
  for (int i = 0; i < 2; ++i) {
    int row = i * 32 + (tid >> 3);
    gl_lds16(Q + base + (size_t)(q0 + row) * 64 + (((tid & 7) ^ (row & 7)) << 3),
             (char*)Qs + i * 4096 + wid * 1024);
  }
#pragma unroll
  for (int i = 0; i < 4; ++i) {
    int row = i * 32 + (tid >> 3);
    gl_lds16(K + base + (size_t)(c0 + row) * 64 + (((tid & 7) ^ (row & 7)) << 3),
             (char*)Ks2 + i * 4096 + wid * 1024);
  }
  __syncthreads();

  f32x4 s[8] = {};
#pragma unroll
  for (int kk = 0; kk < 2; ++kk) {
    const int kc = kk * 32 + (lane >> 4) * 8;
    bf16x8 aq = *(const bf16x8*)(Qs + swzh(wid * 16 + (lane & 15), kc));
#pragma unroll
    for (int n = 0; n < 8; ++n) {
      bf16x8 bk = *(const bf16x8*)(Ks2 + swzh(n * 16 + (lane & 15), kc));
      s[n] = __builtin_amdgcn_mfma_f32_16x16x32_bf16(aq, bk, s[n], 0, 0, 0);
    }
  }

#pragma unroll
  for (int r = 0; r < 4; ++r) {
    const int q = q0 + wid * 16 + ((lane >> 4) << 2) + r;
    const float2 st = stats[b * 2048 + q];
    const float rl = __builtin_amdgcn_rcpf(st.y);
#pragma unroll
    for (int n = 0; n < 8; ++n) {
      const int kp = c0 + n * 16 + (lane & 15);
      out[((size_t)b * 2048 + q) * 2048 + kp] =
          (kp <= q) ? fexp2(s[n][r] - st.x) * rl : 0.f;
    }
  }
}

extern "C" void kernel_launch(void* const* d_in, const int* in_sizes, int n_in,
                              void* d_out, int out_size, void* d_ws,
                              size_t ws_size, hipStream_t stream) {
  (void)in_sizes; (void)n_in; (void)out_size; (void)ws_size;
  const float* key = (const float*)d_in[0];
  const float* value = (const float*)d_in[1];
  const float* query = (const float*)d_in[2];
  const float* Wk = (const float*)d_in[4];
  const float* bk = (const float*)d_in[5];
  const float* Wv = (const float*)d_in[6];
  const float* bv = (const float*)d_in[7];
  const float* Wq = (const float*)d_in[8];
  const float* bq = (const float*)d_in[9];
  const float* Wo = (const float*)d_in[10];
  const float* bo = (const float*)d_in[11];

  char* ws = (char*)d_ws;  // needs ~124 MB
  u16* WtK = (u16*)(ws);
  u16* WtV = (u16*)(ws + (2u << 20));
  u16* WtQ = (u16*)(ws + (4u << 20));
  u16* WtO = (u16*)(ws + (6u << 20));
  u16* Kup = (u16*)(ws + (8u << 20));   // [b][h][l][dh] bf16
  u16* Qup = (u16*)(ws + (24u << 20));  // [b][h][l][dh] bf16
  u16* Vt  = (u16*)(ws + (40u << 20));  // [b][h][dh][l] bf16
  u16* ctx = (u16*)(ws + (56u << 20));  // [b][l][1024] bf16
  float2* stats = (float2*)(ws + (72u << 20));  // [b*2048] (m_log2, lsum)
  u16* Akb = (u16*)(ws + (76u << 20));  // bf16 key   [8192][1024]
  u16* Avb = (u16*)(ws + (92u << 20));  // bf16 value
  u16* Aqb = (u16*)(ws + (108u << 20)); // bf16 query

  prep_k<<<dim3(1024, 1, 7), 256, 0, stream>>>(Wk, Wv, Wq, Wo, WtK, WtV, WtQ,
                                               WtO, key, value, query, Akb,
                                               Avb, Aqb);

  // Q scale folds 1/sqrt(DH) and log2(e) so softmax runs on exp2 directly.
  const float qscale = 0.125f * 1.44269504088896340736f;
  qkvgemm_k<<<dim3(512, 1, 3), 256, 0, stream>>>(
      Akb, Avb, Aqb, WtK, WtV, WtQ, bk, bv, bq, Kup, Vt, Qup, qscale);

  attn_k<<<dim3(64, 16), 512, 0, stream>>>(Qup, Kup, Vt, ctx, stats);

  float* out = (float*)d_out;
  probs_k<<<dim3(16, 32, 4), 256, 0, stream>>>(Qup, Kup, stats,
                                               out + (size_t)8388608);

  outgemm_k<<<512, 256, 0, stream>>>(ctx, WtO, bo, out);
}

// Round 16
// 188.193 us; speedup vs baseline: 1.1419x; 1.0098x over previous
//
#include <hip/hip_runtime.h>
#include <hip/hip_bf16.h>
#include <stdint.h>

typedef unsigned short u16;
typedef unsigned int u32;
typedef __attribute__((ext_vector_type(8))) short bf16x8;
typedef __attribute__((ext_vector_type(4))) float f32x4;
typedef __attribute__((address_space(1))) unsigned int as1u;
typedef __attribute__((address_space(3))) unsigned int as3u;

#define DEV __device__ __forceinline__

DEV u16 f2bf(float f) {
  union { float f; unsigned u; } v; v.f = f;
  unsigned r = v.u + 0x7FFFu + ((v.u >> 16) & 1u);  // RNE
  return (u16)(r >> 16);
}

// hardware packed fp32->bf16 convert (no builtin on gfx950)
DEV u32 cvtpk(float lo, float hi) {
  u32 r;
  asm("v_cvt_pk_bf16_f32 %0, %1, %2" : "=v"(r) : "v"(lo), "v"(hi));
  return r;
}

// bare v_exp_f32 (2^x); args bounded above, underflow-to-0 desired.
DEV float fexp2(float x) {
  float r;
  asm("v_exp_f32 %0, %1" : "=v"(r) : "v"(x));
  return r;
}

DEV void gl_lds16(const void* g, void* l) {
  __builtin_amdgcn_global_load_lds(
      reinterpret_cast<as1u*>(reinterpret_cast<uintptr_t>(g)),
      reinterpret_cast<as3u*>(reinterpret_cast<uintptr_t>(l)), 16, 0, 0);
}

// XOR-swizzled index helpers. Tiles are [rows][64] elements.
DEV int swzh(int r, int c) { return r * 64 + (c ^ ((r & 7) << 3)); }

// XCD swizzle for 512-block GEMM grids.
DEV int xcdswz512(int bid) { return ((bid & 7) << 6) | (bid >> 3); }

// ---------------- prep: weight transpose (z 0-3) + A fp32->bf16 (z 4-6) ----
__global__ __launch_bounds__(256) void prep_k(
    const float* __restrict__ W0, const float* __restrict__ W1,
    const float* __restrict__ W2, const float* __restrict__ W3,
    u16* __restrict__ T0, u16* __restrict__ T1, u16* __restrict__ T2,
    u16* __restrict__ T3, const float* __restrict__ I0,
    const float* __restrict__ I1, const float* __restrict__ I2,
    u16* __restrict__ O0, u16* __restrict__ O1, u16* __restrict__ O2) {
  const int z = blockIdx.z;
  const int tid = threadIdx.x;
  if (z < 4) {
    if (blockIdx.x >= 256) return;
    const float* W = z == 0 ? W0 : z == 1 ? W1 : z == 2 ? W2 : W3;
    u16* Wt = z == 0 ? T0 : z == 1 ? T1 : z == 2 ? T2 : T3;
    __shared__ float t[64][65];
    const int n0 = (blockIdx.x & 15) * 64, k0 = (blockIdx.x >> 4) * 64;
    const int c = tid & 63, r4 = tid >> 6;
#pragma unroll
    for (int i = 0; i < 16; ++i) {
      int r = r4 * 16 + i;
      t[r][c] = W[(size_t)(k0 + r) * 1024 + n0 + c];
    }
    __syncthreads();
#pragma unroll
    for (int i = 0; i < 16; ++i) {
      int r = r4 * 16 + i;
      Wt[(size_t)(n0 + r) * 1024 + k0 + c] = f2bf(t[c][r]);
    }
  } else {
    const float* in = z == 4 ? I0 : z == 5 ? I1 : I2;
    u16* out = z == 4 ? O0 : z == 5 ? O1 : O2;
    const int idx = blockIdx.x * 256 + tid;  // 1024 blocks
#pragma unroll
    for (int j = 0; j < 8; ++j) {
      const int i = j * 262144 + idx;
      float4 x = ((const float4*)in)[i];
      uint2 p;
      p.x = cvtpk(x.x, x.y);
      p.y = cvtpk(x.z, x.w);
      ((uint2*)out)[i] = p;
    }
  }
}

// ---------------- fused QKV projection GEMM, bf16 A, counted-vmcnt dbuf ----
__global__ __launch_bounds__(256) void qkvgemm_k(
    const u16* __restrict__ Akey, const u16* __restrict__ Aval,
    const u16* __restrict__ Aqry, const u16* __restrict__ BtK,
    const u16* __restrict__ BtV, const u16* __restrict__ BtQ,
    const float* __restrict__ bk, const float* __restrict__ bv,
    const float* __restrict__ bq, u16* __restrict__ Kup, u16* __restrict__ Vt,
    u16* __restrict__ Qup, float qscale) {
  constexpr int K = 1024;
  const int z = blockIdx.z;
  const u16* Ah = z == 0 ? Akey : z == 1 ? Aval : Aqry;
  const u16* Bt = z == 0 ? BtK : z == 1 ? BtV : BtQ;
  const float* bias = z == 0 ? bk : z == 1 ? bv : bq;
  u16* Cp = z == 0 ? Kup : z == 1 ? Vt : Qup;
  const float scale = z == 2 ? qscale : 1.0f;

  __shared__ alignas(16) char smem[65536];  // [buf][A 16K | B 16K]

  const int tid = threadIdx.x;
  const int lane = tid & 63, wid = tid >> 6;
  const int swz = xcdswz512(blockIdx.x);
  const int brow = (swz >> 3) * 128;
  const int bcol = (swz & 7) * 128;
  const int wr = (wid >> 1) * 64, wc = (wid & 1) * 64;

  f32x4 acc[4][4] = {};

  auto stage = [&](int kt, int buf) {
#pragma unroll
    for (int i = 0; i < 4; ++i) {
      int row = i * 32 + (tid >> 3);
      const int sc = ((tid & 7) ^ (row & 7)) << 3;
      gl_lds16(Ah + (size_t)(brow + row) * K + kt + sc,
               smem + buf * 32768 + i * 4096 + wid * 1024);
      gl_lds16(Bt + (size_t)(bcol + row) * K + kt + sc,
               smem + buf * 32768 + 16384 + i * 4096 + wid * 1024);
    }
  };

  stage(0, 0);   // 8 loads/wave
  stage(64, 1);  // 8 more in flight

  int cur = 0;
  for (int kt = 0; kt < K; kt += 64) {
    if (kt == K - 64)
      asm volatile("s_waitcnt vmcnt(0)" ::: "memory");
    else
      asm volatile("s_waitcnt vmcnt(8)" ::: "memory");
    __builtin_amdgcn_s_barrier();  // tile kt visible to all waves

    const u16* Ash = (const u16*)(smem + cur * 32768);
    const u16* Bs = (const u16*)(smem + cur * 32768 + 16384);
#pragma unroll
    for (int kk = 0; kk < 2; ++kk) {
      const int kcol = kk * 32 + (lane >> 4) * 8;
      bf16x8 a[4], bfr[4];
#pragma unroll
      for (int m = 0; m < 4; ++m)
        a[m] = *(const bf16x8*)(Ash + swzh(wr + m * 16 + (lane & 15), kcol));
#pragma unroll
      for (int n = 0; n < 4; ++n)
        bfr[n] = *(const bf16x8*)(Bs + swzh(wc + n * 16 + (lane & 15), kcol));
#pragma unroll
      for (int m = 0; m < 4; ++m)
#pragma unroll
        for (int n = 0; n < 4; ++n)
          acc[m][n] = __builtin_amdgcn_mfma_f32_16x16x32_bf16(
              a[m], bfr[n], acc[m][n], 0, 0, 0);
    }
    asm volatile("s_waitcnt lgkmcnt(0)" ::: "memory");
    __builtin_amdgcn_s_barrier();  // all waves done reading buf cur
    if (kt + 128 < K) stage(kt + 128, cur);  // overwrite consumed buffer
    cur ^= 1;
  }

  const int g = lane >> 4;
  if (z == 1) {
    // V: LDS transpose -> coalesced stores along l
    u16* T = (u16*)smem;
#pragma unroll
    for (int m = 0; m < 4; ++m) {
      const int row0 = wr + m * 16 + g * 4;  // l_local
#pragma unroll
      for (int n = 0; n < 4; ++n) {
        const int col = wc + n * 16 + (lane & 15);  // dh_local
        const float bv2 = bias[bcol + col];
        uint2 p;
        p.x = cvtpk(acc[m][n][0] + bv2, acc[m][n][1] + bv2);
        p.y = cvtpk(acc[m][n][2] + bv2, acc[m][n][3] + bv2);
        *(uint2*)((char*)T + col * 256 + ((row0 * 2) ^ ((col & 7) << 4))) = p;
      }
    }
    __syncthreads();
    const int bI = brow >> 11, l0 = brow & 2047;
#pragma unroll
    for (int i = 0; i < 8; ++i) {
      const int rr = i * 16 + (tid >> 4);
      const int xb = (tid & 15) * 16;
      uint4 v = *(uint4*)((char*)T + rr * 256 + (xb ^ ((rr & 7) << 4)));
      const int colg = bcol + rr;
      const int hh = colg >> 6, dh = colg & 63;
      *(uint4*)(&Cp[((size_t)((bI << 4) + hh) * 64 + dh) * 2048 + l0 +
                    (xb >> 1)]) = v;
    }
  } else {
#pragma unroll
    for (int m = 0; m < 4; ++m) {
      const int row0 = brow + wr + m * 16 + (g << 2);
#pragma unroll
      for (int n = 0; n < 4; ++n) {
        const int col = bcol + wc + n * 16 + (lane & 15);
        const float bv2 = bias[col];
        const int h = col >> 6, dh = col & 63;
#pragma unroll
        for (int r = 0; r < 4; ++r) {
          const int row = row0 + r;
          const float val = (acc[m][n][r] + bv2) * scale;
          const int b = row >> 11, l = row & 2047;
          Cp[((size_t)((b << 4) + h) * 2048 + l) * 64 + dh] = f2bf(val);
        }
      }
    }
  }
}

// ---------------- flash attention: KVBLK=128, MFMA l-sum -------------------
__global__ __launch_bounds__(512, 4) void attn_k(const u16* __restrict__ Q,
                                                 const u16* __restrict__ K,
                                                 const u16* __restrict__ Vt,
                                                 u16* __restrict__ ctx,
                                                 float2* __restrict__ stats) {
  const int tid = threadIdx.x, lane = tid & 63, wid = tid >> 6;
  const int bh = blockIdx.x;
  const int qt = 15 - (int)blockIdx.y;  // heavy blocks first
  const int b = bh >> 4, h = bh & 15;
  const size_t base = (size_t)bh * 2048 * 64;

  __shared__ alignas(16) u16 Ks[2][8192], Vs[2][8192], Ps[8192];

  bf16x8 qf[2];
  {
    const u16* qp = Q + base +
                    (size_t)(qt * 128 + wid * 16 + (lane & 15)) * 64 +
                    ((lane >> 4) << 3);
    qf[0] = *(const bf16x8*)(qp);
    qf[1] = *(const bf16x8*)(qp + 32);
  }
  bf16x8 ones;
#pragma unroll
  for (int i = 0; i < 8; ++i) ones[i] = (short)0x3F80;  // bf16 1.0

  const int srowK = tid >> 3;
  const int scolK = ((tid & 7) ^ (srowK & 7)) << 3;
  const int srowV = tid >> 4;
  const int scolV = ((tid & 15) ^ (srowV & 7)) << 3;
  auto stage = [&](int kt, int buf) {
#pragma unroll
    for (int i = 0; i < 2; ++i)
      gl_lds16(K + base + (size_t)(kt * 128 + i * 64 + srowK) * 64 + scolK,
               (char*)Ks + buf * 16384 + i * 8192 + tid * 16);
#pragma unroll
    for (int i = 0; i < 2; ++i)
      gl_lds16(Vt + base + (size_t)(i * 32 + srowV) * 2048 + kt * 128 + scolV,
               (char*)Vs + buf * 16384 + i * 8192 + tid * 16);
  };

  f32x4 acc_o[4] = {}, acc_l = {};
  float m_run = -1e30f;
  const int q = qt * 128 + wid * 16 + (lane & 15);
  const int g = lane >> 4;
  const int l7 = lane & 7;

  stage(0, 0);
  __syncthreads();

  int cur = 0;
  for (int kt = 0; kt <= qt; ++kt) {
    if (kt < qt) stage(kt + 1, cur ^ 1);

    f32x4 s[8] = {};
#pragma unroll
    for (int kk = 0; kk < 2; ++kk) {
      const int kcb = kk * 64 + g * 16;
#pragma unroll
      for (int n2 = 0; n2 < 8; ++n2) {
        const int row = n2 * 16 + (lane & 15);
        bf16x8 kf = *(const bf16x8*)((char*)Ks + cur * 16384 + row * 128 +
                                     (kcb ^ ((row & 7) << 4)));
        s[n2] = __builtin_amdgcn_mfma_f32_16x16x32_bf16(kf, qf[kk], s[n2],
                                                        0, 0, 0);
      }
    }

    if (kt == qt) {  // diagonal tile: mask kv > q
      const int kb = kt * 128 + g * 4;
#pragma unroll
      for (int n2 = 0; n2 < 8; ++n2)
#pragma unroll
        for (int r = 0; r < 4; ++r)
          if (kb + n2 * 16 + r > q) s[n2][r] = -1e30f;
    }

    float mn0 = fmaxf(fmaxf(fmaxf(s[0][0], s[0][1]), fmaxf(s[0][2], s[0][3])),
                      fmaxf(fmaxf(s[1][0], s[1][1]), fmaxf(s[1][2], s[1][3])));
    float mn1 = fmaxf(fmaxf(fmaxf(s[2][0], s[2][1]), fmaxf(s[2][2], s[2][3])),
                      fmaxf(fmaxf(s[3][0], s[3][1]), fmaxf(s[3][2], s[3][3])));
    float mn2 = fmaxf(fmaxf(fmaxf(s[4][0], s[4][1]), fmaxf(s[4][2], s[4][3])),
                      fmaxf(fmaxf(s[5][0], s[5][1]), fmaxf(s[5][2], s[5][3])));
    float mn3 = fmaxf(fmaxf(fmaxf(s[6][0], s[6][1]), fmaxf(s[6][2], s[6][3])),
                      fmaxf(fmaxf(s[7][0], s[7][1]), fmaxf(s[7][2], s[7][3])));
    float mx = fmaxf(fmaxf(mn0, mn1), fmaxf(mn2, mn3));
    mx = fmaxf(mx, __shfl_xor(mx, 16, 64));
    mx = fmaxf(mx, __shfl_xor(mx, 32, 64));

    if (__any(mx - m_run > 8.0f)) {  // defer-max (log2 units)
      const float mn = fmaxf(m_run, mx);
      const float alpha = fexp2(m_run - mn);
      m_run = mn;
#pragma unroll
      for (int r = 0; r < 4; ++r) {
        const float ar = __shfl(alpha, (g << 2) + r, 64);
        acc_l[r] *= ar;
#pragma unroll
        for (int n = 0; n < 4; ++n) acc_o[n][r] *= ar;
      }
    }

#pragma unroll
    for (int n2 = 0; n2 < 8; ++n2)
#pragma unroll
      for (int r = 0; r < 4; ++r) s[n2][r] = fexp2(s[n2][r] - m_run);

#pragma unroll
    for (int hf = 0; hf < 2; ++hf) {
#pragma unroll
      for (int n3 = 0; n3 < 4; ++n3) {
        const int n2 = hf * 4 + n3;
        union { u32 w[2]; uint2 u; } pk;
        pk.w[0] = cvtpk(s[n2][0], s[n2][1]);
        pk.w[1] = cvtpk(s[n2][2], s[n2][3]);
        *(uint2*)((char*)Ps + wid * 2048 + (lane & 15) * 128 +
                  ((n3 * 32 + g * 8) ^ (l7 << 4))) = pk.u;
      }
#pragma unroll
      for (int kk2 = 0; kk2 < 2; ++kk2) {
        bf16x8 pf = *(const bf16x8*)((char*)Ps + wid * 2048 +
                                     (lane & 15) * 128 +
                                     ((kk2 * 64 + g * 16) ^ (l7 << 4)));
        const int kvb = hf * 128 + kk2 * 64 + g * 16;
#pragma unroll
        for (int n = 0; n < 4; ++n) {
          const int dh = n * 16 + (lane & 15);
          bf16x8 vf = *(const bf16x8*)((char*)Vs + cur * 16384 + dh * 256 +
                                       (kvb ^ ((dh & 7) << 4)));
          acc_o[n] = __builtin_amdgcn_mfma_f32_16x16x32_bf16(pf, vf, acc_o[n],
                                                             0, 0, 0);
        }
        acc_l = __builtin_amdgcn_mfma_f32_16x16x32_bf16(pf, ones, acc_l,
                                                        0, 0, 0);
      }
    }
    __syncthreads();
    cur ^= 1;
  }

#pragma unroll
  for (int r = 0; r < 4; ++r) {
    const float linv = __builtin_amdgcn_rcpf(acc_l[r]);
    const int qo = qt * 128 + wid * 16 + (g << 2) + r;
#pragma unroll
    for (int n = 0; n < 4; ++n) {
      const int dh = n * 16 + (lane & 15);
      ctx[((size_t)(b * 2048 + qo)) * 1024 + h * 64 + dh] =
          f2bf(acc_o[n][r] * linv);
    }
  }
  if (h == 0) {
    float mr[4];
#pragma unroll
    for (int r = 0; r < 4; ++r) mr[r] = __shfl(m_run, (g << 2) + r, 64);
    if ((lane & 15) == 0) {
#pragma unroll
      for (int r = 0; r < 4; ++r) {
        const int qo = qt * 128 + wid * 16 + (g << 2) + r;
        stats[b * 2048 + qo] = make_float2(mr[r], acc_l[r]);
      }
    }
  }
}

// ---------------- fused epilogue: outgemm (x<512) + top_attn probs ---------
// Both depend only on attn_k outputs and use complementary resources
// (outgemm: MFMA-bound; probs: write-BW-bound) -> one dispatch co-schedules.
__global__ __launch_bounds__(256) void epi_k(
    const u16* __restrict__ Ah, const u16* __restrict__ Bt,
    const float* __restrict__ bias, float* __restrict__ Cp,
    const u16* __restrict__ Q, const u16* __restrict__ K,
    const float2* __restrict__ stats, float* __restrict__ pout) {
  constexpr int KD = 1024;
  __shared__ alignas(16) char smem[65536];
  const int tid = threadIdx.x, lane = tid & 63, wid = tid >> 6;

  if (blockIdx.x < 512) {
    // ---- outgemm role (counted-vmcnt dbuf, unchanged logic) ----
    const int swz = xcdswz512(blockIdx.x);
    const int brow = (swz >> 3) * 128;
    const int bcol = (swz & 7) * 128;
    const int wr = (wid >> 1) * 64, wc = (wid & 1) * 64;

    f32x4 acc[4][4] = {};

    auto stage = [&](int kt, int buf) {
#pragma unroll
      for (int i = 0; i < 4; ++i) {
        int row = i * 32 + (tid >> 3);
        const int sc = ((tid & 7) ^ (row & 7)) << 3;
        gl_lds16(Ah + (size_t)(brow + row) * KD + kt + sc,
                 smem + buf * 32768 + i * 4096 + wid * 1024);
        gl_lds16(Bt + (size_t)(bcol + row) * KD + kt + sc,
                 smem + buf * 32768 + 16384 + i * 4096 + wid * 1024);
      }
    };

    stage(0, 0);
    stage(64, 1);

    int cur = 0;
    for (int kt = 0; kt < KD; kt += 64) {
      if (kt == KD - 64)
        asm volatile("s_waitcnt vmcnt(0)" ::: "memory");
      else
        asm volatile("s_waitcnt vmcnt(8)" ::: "memory");
      __builtin_amdgcn_s_barrier();

      const u16* Ash = (const u16*)(smem + cur * 32768);
      const u16* Bs = (const u16*)(smem + cur * 32768 + 16384);
#pragma unroll
      for (int kk = 0; kk < 2; ++kk) {
        const int kcol = kk * 32 + (lane >> 4) * 8;
        bf16x8 a[4], bfr[4];
#pragma unroll
        for (int m = 0; m < 4; ++m)
          a[m] = *(const bf16x8*)(Ash + swzh(wr + m * 16 + (lane & 15), kcol));
#pragma unroll
        for (int n = 0; n < 4; ++n)
          bfr[n] = *(const bf16x8*)(Bs + swzh(wc + n * 16 + (lane & 15), kcol));
#pragma unroll
        for (int m = 0; m < 4; ++m)
#pragma unroll
          for (int n = 0; n < 4; ++n)
            acc[m][n] = __builtin_amdgcn_mfma_f32_16x16x32_bf16(
                a[m], bfr[n], acc[m][n], 0, 0, 0);
      }
      asm volatile("s_waitcnt lgkmcnt(0)" ::: "memory");
      __builtin_amdgcn_s_barrier();
      if (kt + 128 < KD) stage(kt + 128, cur);
      cur ^= 1;
    }

#pragma unroll
    for (int m = 0; m < 4; ++m) {
      const int row0 = brow + wr + m * 16 + ((lane >> 4) << 2);
#pragma unroll
      for (int n = 0; n < 4; ++n) {
        const int col = bcol + wc + n * 16 + (lane & 15);
        const float bv2 = bias[col];
#pragma unroll
        for (int r = 0; r < 4; ++r)
          Cp[(size_t)(row0 + r) * 1024 + col] = acc[m][n][r] + bv2;
      }
    }
  } else {
    // ---- probs role (head-0 top_attn, unchanged logic) ----
    const int bid = blockIdx.x - 512;
    const int kt2 = bid & 15, qt = (bid >> 4) & 31, b = bid >> 9;
    const int q0 = qt * 64, c0 = kt2 * 128;
    float* ot = pout + ((size_t)b * 2048 + q0) * 2048 + c0;

    if (c0 > q0 + 63) {  // whole tile masked -> zero-fill
      const float4 z = make_float4(0.f, 0.f, 0.f, 0.f);
#pragma unroll
      for (int i = 0; i < 8; ++i) {
        const int idx = i * 256 + tid;
        *(float4*)(ot + (size_t)(idx >> 5) * 2048 + ((idx & 31) << 2)) = z;
      }
      return;
    }

    u16* Qs = (u16*)smem;            // 8KB
    u16* Ks2 = (u16*)(smem + 8192);  // 16KB
    const size_t base = (size_t)(b * 16) * 2048 * 64;  // h = 0
#pragma unroll
    for (int i = 0; i < 2; ++i) {
      int row = i * 32 + (tid >> 3);
      gl_lds16(Q + base + (size_t)(q0 + row) * 64 +
                   (((tid & 7) ^ (row & 7)) << 3),
               (char*)Qs + i * 4096 + wid * 1024);
    }
#pragma unroll
    for (int i = 0; i < 4; ++i) {
      int row = i * 32 + (tid >> 3);
      gl_lds16(K + base + (size_t)(c0 + row) * 64 +
                   (((tid & 7) ^ (row & 7)) << 3),
               (char*)Ks2 + i * 4096 + wid * 1024);
    }
    __syncthreads();

    f32x4 s[8] = {};
#pragma unroll
    for (int kk = 0; kk < 2; ++kk) {
      const int kc = kk * 32 + (lane >> 4) * 8;
      bf16x8 aq = *(const bf16x8*)(Qs + swzh(wid * 16 + (lane & 15), kc));
#pragma unroll
      for (int n = 0; n < 8; ++n) {
        bf16x8 bk = *(const bf16x8*)(Ks2 + swzh(n * 16 + (lane & 15), kc));
        s[n] = __builtin_amdgcn_mfma_f32_16x16x32_bf16(aq, bk, s[n], 0, 0, 0);
      }
    }

#pragma unroll
    for (int r = 0; r < 4; ++r) {
      const int q = q0 + wid * 16 + ((lane >> 4) << 2) + r;
      const float2 st = stats[b * 2048 + q];
      const float rl = __builtin_amdgcn_rcpf(st.y);
#pragma unroll
      for (int n = 0; n < 8; ++n) {
        const int kp = c0 + n * 16 + (lane & 15);
        pout[((size_t)b * 2048 + q) * 2048 + kp] =
            (kp <= q) ? fexp2(s[n][r] - st.x) * rl : 0.f;
      }
    }
  }
}

extern "C" void kernel_launch(void* const* d_in, const int* in_sizes, int n_in,
                              void* d_out, int out_size, void* d_ws,
                              size_t ws_size, hipStream_t stream) {
  (void)in_sizes; (void)n_in; (void)out_size; (void)ws_size;
  const float* key = (const float*)d_in[0];
  const float* value = (const float*)d_in[1];
  const float* query = (const float*)d_in[2];
  const float* Wk = (const float*)d_in[4];
  const float* bk = (const float*)d_in[5];
  const float* Wv = (const float*)d_in[6];
  const float* bv = (const float*)d_in[7];
  const float* Wq = (const float*)d_in[8];
  const float* bq = (const float*)d_in[9];
  const float* Wo = (const float*)d_in[10];
  const float* bo = (const float*)d_in[11];

  char* ws = (char*)d_ws;  // needs ~124 MB
  u16* WtK = (u16*)(ws);
  u16* WtV = (u16*)(ws + (2u << 20));
  u16* WtQ = (u16*)(ws + (4u << 20));
  u16* WtO = (u16*)(ws + (6u << 20));
  u16* Kup = (u16*)(ws + (8u << 20));   // [b][h][l][dh] bf16
  u16* Qup = (u16*)(ws + (24u << 20));  // [b][h][l][dh] bf16
  u16* Vt  = (u16*)(ws + (40u << 20));  // [b][h][dh][l] bf16
  u16* ctx = (u16*)(ws + (56u << 20));  // [b][l][1024] bf16
  float2* stats = (float2*)(ws + (72u << 20));  // [b*2048] (m_log2, lsum)
  u16* Akb = (u16*)(ws + (76u << 20));  // bf16 key   [8192][1024]
  u16* Avb = (u16*)(ws + (92u << 20));  // bf16 value
  u16* Aqb = (u16*)(ws + (108u << 20)); // bf16 query

  prep_k<<<dim3(1024, 1, 7), 256, 0, stream>>>(Wk, Wv, Wq, Wo, WtK, WtV, WtQ,
                                               WtO, key, value, query, Akb,
                                               Avb, Aqb);

  // Q scale folds 1/sqrt(DH) and log2(e) so softmax runs on exp2 directly.
  const float qscale = 0.125f * 1.44269504088896340736f;
  qkvgemm_k<<<dim3(512, 1, 3), 256, 0, stream>>>(
      Akb, Avb, Aqb, WtK, WtV, WtQ, bk, bv, bq, Kup, Vt, Qup, qscale);

  attn_k<<<dim3(64, 16), 512, 0, stream>>>(Qup, Kup, Vt, ctx, stats);

  float* out = (float*)d_out;
  epi_k<<<2560, 256, 0, stream>>>(ctx, WtO, bo, out, Qup, Kup, stats,
                                  out + (size_t)8388608);
}